// Round 6
// baseline (305.868 us; speedup 1.0000x reference)
//
#include <hip/hip_runtime.h>

#define D_MODEL 2048
#define SEQ 2048
#define BATCH 2
#define NH 16
#define NKV 4
#define HD 128
#define KVD (NKV * HD)              // 512
#define QKVN (D_MODEL + 2 * KVD)    // 3072
#define MROWS (BATCH * SEQ)         // 4096

typedef __attribute__((ext_vector_type(8))) short short8;
typedef __attribute__((ext_vector_type(4))) float f32x4;

__device__ __forceinline__ unsigned short f2bf(float f) {
    union { float f; unsigned int u; } v; v.f = f;
    unsigned int r = (v.u + 0x7FFFu + ((v.u >> 16) & 1u)) >> 16;
    return (unsigned short)r;
}

// round-to-nearest for NON-NEGATIVE floats only (2 ops)
__device__ __forceinline__ unsigned short f2bf_pos(float f) {
    union { float f; unsigned int u; } v; v.f = f;
    return (unsigned short)((v.u + 0x8000u) >> 16);
}

__device__ __forceinline__ float bf2f(unsigned short u) {
    union { float f; unsigned int i; } v; v.i = ((unsigned int)u) << 16;
    return v.f;
}

__device__ __forceinline__ void async16(const void* g, void* l) {
    __builtin_amdgcn_global_load_lds((const __attribute__((address_space(1))) void*)g,
                                     (__attribute__((address_space(3))) void*)l, 16, 0, 0);
}

// ------- merged f32->bf16 cast for x,Wq,Wk,Wv,Wp + rope cos/sin table (one launch) ----
__global__ __launch_bounds__(256) void cast_all(const float* __restrict__ x,
                                                const float* __restrict__ wq,
                                                const float* __restrict__ wk,
                                                const float* __restrict__ wv,
                                                const float* __restrict__ wp,
                                                unsigned short* __restrict__ xb,
                                                unsigned short* __restrict__ wqkv,
                                                unsigned short* __restrict__ wpb,
                                                float* __restrict__ ropec,
                                                float* __restrict__ ropes) {
    int i = blockIdx.x * 256 + threadIdx.x;  // float4 index, regions block-aligned
    if (i < 4718592) {
        const float4* s; ushort4* d; int j;
        if (i < 2097152)      { s = (const float4*)x;  d = (ushort4*)xb;             j = i; }
        else if (i < 3145728) { s = (const float4*)wq; d = (ushort4*)wqkv;           j = i - 2097152; }
        else if (i < 3407872) { s = (const float4*)wk; d = (ushort4*)wqkv + 1048576; j = i - 3145728; }
        else if (i < 3670016) { s = (const float4*)wv; d = (ushort4*)wqkv + 1310720; j = i - 3407872; }
        else                  { s = (const float4*)wp; d = (ushort4*)wpb;            j = i - 3670016; }
        float4 v = s[j];
        ushort4 o;
        o.x = f2bf(v.x); o.y = f2bf(v.y); o.z = f2bf(v.z); o.w = f2bf(v.w);
        d[j] = o;
    } else {
        int j = i - 4718592;          // 0..131071: s = j>>6, freq = j&63
        int s  = j >> 6;
        int f  = j & 63;
        float ang = (float)s * __builtin_amdgcn_exp2f(-(float)f * 0.20761871f);
        float sn, cs;
        sincosf(ang, &sn, &cs);
        ropec[j] = cs;
        ropes[j] = sn;
    }
}

// ---------------- GEMM1 fused: qkv = x @ Wqkv^T, then rmsnorm/rope/gain (q,k) or
// transpose (v) in-epilogue. Column tile (128) == one head. ----------------
__global__ __launch_bounds__(256) void gemm_qkv(const unsigned short* __restrict__ A,
                                                const unsigned short* __restrict__ W,
                                                const float* __restrict__ gain,
                                                const float* __restrict__ ropec,
                                                const float* __restrict__ ropes,
                                                unsigned short* __restrict__ qbuf,
                                                unsigned short* __restrict__ kbuf,
                                                unsigned short* __restrict__ vtb) {
    __shared__ unsigned short smem[128 * 137];   // 35 KB; reused: staging then out-tile
    unsigned short* As = smem;
    unsigned short* Bs = smem + 4096;
    unsigned short* tile = smem;                 // 128 x 137
    const int K = D_MODEL;
    const int tid  = threadIdx.x;
    const int lane = tid & 63;
    const int wave = tid >> 6;
    const int qm   = lane & 15;
    const int quad = lane >> 4;
    const int m0 = blockIdx.y * 128;
    const int bx = blockIdx.x;
    const int n0 = bx * 128;
    const int wm = (wave >> 1) * 64;
    const int wn = (wave & 1) * 64;

    f32x4 acc[4][4];
#pragma unroll
    for (int i = 0; i < 4; i++)
#pragma unroll
        for (int j = 0; j < 4; j++) acc[i][j] = (f32x4){0.f, 0.f, 0.f, 0.f};

    const int r1 = tid >> 2;
    const int c1 = (((tid & 3) ^ ((r1 >> 1) & 3)) * 8);
    const unsigned short* Ag = A + (size_t)(m0 + r1) * K + c1;
    const unsigned short* Wg = W + (size_t)(n0 + r1) * K + c1;
    unsigned short* AsW = &As[wave * 512];
    unsigned short* BsW = &Bs[wave * 512];
    const int swq = ((qm >> 1) & 3) * 8;

    for (int kt = 0; kt < K; kt += 32) {
        async16(Ag,                  AsW);
        async16(Ag + (size_t)64 * K, AsW + 2048);
        async16(Wg,                  BsW);
        async16(Wg + (size_t)64 * K, BsW + 2048);
        Ag += 32; Wg += 32;
        __syncthreads();
        short8 af[4], bfr[4];
#pragma unroll
        for (int mi = 0; mi < 4; mi++)
            af[mi] = *(const short8*)&As[(wm + mi * 16 + qm) * 32 + (quad * 8 ^ swq)];
#pragma unroll
        for (int ni = 0; ni < 4; ni++)
            bfr[ni] = *(const short8*)&Bs[(wn + ni * 16 + qm) * 32 + (quad * 8 ^ swq)];
#pragma unroll
        for (int mi = 0; mi < 4; mi++)
#pragma unroll
            for (int ni = 0; ni < 4; ni++)
                acc[mi][ni] = __builtin_amdgcn_mfma_f32_16x16x32_bf16(af[mi], bfr[ni], acc[mi][ni], 0, 0, 0);
        __syncthreads();
    }

#pragma unroll
    for (int mi = 0; mi < 4; mi++)
#pragma unroll
        for (int r = 0; r < 4; r++) {
            int row = wm + mi * 16 + quad * 4 + r;
#pragma unroll
            for (int ni = 0; ni < 4; ni++)
                tile[row * 137 + wn + ni * 16 + qm] = f2bf(acc[mi][ni][r]);
        }
    __syncthreads();

    const int s_base = m0 & 2047;
    const int bb = m0 >> 11;
    if (bx < 20) {
        const bool isq = bx < 16;
        const float g = isq ? gain[bx] * 0.12751744f : 1.0f;  // (1/sqrt(128))*log2e folded
        unsigned short* dst = isq
            ? qbuf + ((size_t)(bb * NH + bx) * SEQ + s_base) * HD
            : kbuf + ((size_t)(bb * NKV + (bx - 16)) * SEQ + s_base) * HD;
        const float* ct = ropec + (size_t)s_base * 64 + lane;
        const float* st = ropes + (size_t)s_base * 64 + lane;
#pragma unroll 4
        for (int rr = 0; rr < 32; rr++) {
            int row = wave * 32 + rr;
            float cs = ct[(size_t)row * 64];
            float sn = st[(size_t)row * 64];
            float x1 = bf2f(tile[row * 137 + lane]);
            float x2 = bf2f(tile[row * 137 + 64 + lane]);
            float ss = x1 * x1 + x2 * x2;
            ss += __shfl_xor(ss, 1);  ss += __shfl_xor(ss, 2);  ss += __shfl_xor(ss, 4);
            ss += __shfl_xor(ss, 8);  ss += __shfl_xor(ss, 16); ss += __shfl_xor(ss, 32);
            float rs = rsqrtf(ss * (1.0f / 128.0f) + 1.1920929e-07f);
            float a1 = x1 * rs, a2 = x2 * rs;
            float o1 = (a1 * cs + a2 * sn) * g;
            float o2 = (a2 * cs - a1 * sn) * g;
            dst[(size_t)row * HD + lane]      = f2bf(o1);
            dst[(size_t)row * HD + 64 + lane] = f2bf(o2);
        }
    } else {
        const int hk = bx - 20;
        unsigned short* dst = vtb + ((size_t)(bb * NKV + hk) * HD) * SEQ + s_base;
        const int sc = (tid & 31) * 4;
        const int d0 = tid >> 5;
#pragma unroll
        for (int i = 0; i < 16; i++) {
            int d = d0 + 8 * i;
            ushort4 ov;
            ov.x = tile[(sc + 0) * 137 + d];
            ov.y = tile[(sc + 1) * 137 + d];
            ov.z = tile[(sc + 2) * 137 + d];
            ov.w = tile[(sc + 3) * 137 + d];
            *(ushort4*)(dst + (size_t)d * SEQ + sc) = ov;
        }
    }
}

// ---------------- GEMM2: C[M,N] = A[M,K] * W[N,K]^T  (bf16 in, fp32 out) --------------
__global__ __launch_bounds__(256) void gemm_bt(const unsigned short* __restrict__ A,
                                               const unsigned short* __restrict__ W,
                                               float* __restrict__ C, int M, int N, int K) {
    __shared__ unsigned short As[128 * 32];
    __shared__ unsigned short Bs[128 * 32];
    const int tid  = threadIdx.x;
    const int lane = tid & 63;
    const int wave = tid >> 6;
    const int qm   = lane & 15;
    const int quad = lane >> 4;
    const int m0 = blockIdx.y * 128;
    const int n0 = blockIdx.x * 128;
    const int wm = (wave >> 1) * 64;
    const int wn = (wave & 1) * 64;

    f32x4 acc[4][4];
#pragma unroll
    for (int i = 0; i < 4; i++)
#pragma unroll
        for (int j = 0; j < 4; j++) acc[i][j] = (f32x4){0.f, 0.f, 0.f, 0.f};

    const int r1 = tid >> 2;
    const int c1 = (((tid & 3) ^ ((r1 >> 1) & 3)) * 8);
    const unsigned short* Ag = A + (size_t)(m0 + r1) * K + c1;
    const unsigned short* Wg = W + (size_t)(n0 + r1) * K + c1;
    unsigned short* AsW = &As[wave * 512];
    unsigned short* BsW = &Bs[wave * 512];
    const int swq = ((qm >> 1) & 3) * 8;

    for (int kt = 0; kt < K; kt += 32) {
        async16(Ag,                  AsW);
        async16(Ag + (size_t)64 * K, AsW + 2048);
        async16(Wg,                  BsW);
        async16(Wg + (size_t)64 * K, BsW + 2048);
        Ag += 32; Wg += 32;
        __syncthreads();
        short8 af[4], bfr[4];
#pragma unroll
        for (int mi = 0; mi < 4; mi++)
            af[mi] = *(const short8*)&As[(wm + mi * 16 + qm) * 32 + (quad * 8 ^ swq)];
#pragma unroll
        for (int ni = 0; ni < 4; ni++)
            bfr[ni] = *(const short8*)&Bs[(wn + ni * 16 + qm) * 32 + (quad * 8 ^ swq)];
#pragma unroll
        for (int mi = 0; mi < 4; mi++)
#pragma unroll
            for (int ni = 0; ni < 4; ni++)
                acc[mi][ni] = __builtin_amdgcn_mfma_f32_16x16x32_bf16(af[mi], bfr[ni], acc[mi][ni], 0, 0, 0);
        __syncthreads();
    }
#pragma unroll
    for (int mi = 0; mi < 4; mi++) {
#pragma unroll
        for (int r = 0; r < 4; r++) {
            int row = m0 + wm + mi * 16 + quad * 4 + r;
            float* Crow = C + (size_t)row * N + n0 + wn + qm;
#pragma unroll
            for (int ni = 0; ni < 4; ni++) Crow[ni * 16] = acc[mi][ni][r];
        }
    }
}

// ------- flash attention v6: Q32 per wave (K/V fragments shared by 2 row-sets) --------
// LDS-read per FLOP halved vs v5; BKV=64; fixed-cap softmax; 512 blocks (2/CU).
__global__ __launch_bounds__(256, 2) void attn(const unsigned short* __restrict__ qb,
                                               const unsigned short* __restrict__ kb,
                                               const unsigned short* __restrict__ vt,
                                               const float* __restrict__ gain,
                                               unsigned short* __restrict__ y) {
    __shared__ unsigned short Ks[8192];      // 64 kv-rows x 128 d, swizzled (16 KB)
    __shared__ unsigned short Vs[8192];      // 128 d-rows x 64 s, swizzled (16 KB)
    __shared__ unsigned short plds[4][2048]; // wave-private P: 32 x 64, swizzled (16 KB)
    const int tid  = threadIdx.x;
    const int lane = tid & 63;
    const int wave = tid >> 6;
    const int bh   = blockIdx.x & 31;
    const int g4   = blockIdx.x >> 5;                  // 0..15
    const int qt128 = (g4 < 8) ? g4 : 23 - g4;         // paired: i and i+256 sum to 15
    const int h = bh & 15;
    const int b = bh >> 4;
    const int qm   = lane & 15;
    const int quad = lane >> 4;
    const int q0 = qt128 * 128;
    const int qa = q0 + wave * 32;                     // set a: qa.., set b: qa+16..
    const float M = 17.0f * fabsf(gain[h]);

    const unsigned short* Qp = qb + (((size_t)(b * NH + h)) * SEQ + qa) * HD;
    const unsigned short* Kp = kb + ((size_t)(b * NKV + (h >> 2))) * SEQ * HD;
    const unsigned short* Vp = vt + ((size_t)(b * NKV + (h >> 2))) * HD * SEQ;

    short8 qf[2][4];
#pragma unroll
    for (int s2 = 0; s2 < 2; s2++)
#pragma unroll
        for (int c = 0; c < 4; c++)
            qf[s2][c] = *(const short8*)(Qp + (size_t)(s2 * 16 + qm) * HD + c * 32 + quad * 8);

    f32x4 o[2][8];
#pragma unroll
    for (int s2 = 0; s2 < 2; s2++)
#pragma unroll
        for (int t = 0; t < 8; t++) o[s2][t] = (f32x4){0.f, 0.f, 0.f, 0.f};
    float lr[2][4] = {{0.f, 0.f, 0.f, 0.f}, {0.f, 0.f, 0.f, 0.f}};

    const unsigned short* KsA = Kp + (size_t)(tid >> 4) * HD + (((tid & 15) ^ (tid >> 4)) & 15) * 8;
    const unsigned short* VsA = Vp + (size_t)(tid >> 3) * SEQ + (((tid & 7) ^ ((tid >> 3) & 7)) * 8);
    char* KsB = (char*)Ks + wave * 1024;
    char* VsB = (char*)Vs + wave * 1024;
    unsigned short* P = &plds[wave][0];

    const int kvend = q0 + 128;
    for (int kv0 = 0; kv0 < kvend; kv0 += 64) {
#pragma unroll
        for (int i = 0; i < 4; i++) {
            async16(KsA + (size_t)(16 * i) * HD,  KsB + i * 4096);
            async16(VsA + (size_t)(32 * i) * SEQ, VsB + i * 4096);
        }
        KsA += (size_t)64 * HD;
        VsA += 64;
        __syncthreads();

        if (kv0 < qa + 32) {   // wave-uniform; both row-sets active or both inactive
            f32x4 s[2][4];
#pragma unroll
            for (int s2 = 0; s2 < 2; s2++)
#pragma unroll
                for (int g = 0; g < 4; g++) s[s2][g] = (f32x4){0.f, 0.f, 0.f, 0.f};
#pragma unroll
            for (int c = 0; c < 4; c++) {
#pragma unroll
                for (int g = 0; g < 4; g++) {
                    short8 kf = *(const short8*)&Ks[(g * 16 + qm) * 128 + (((c * 4 + quad) ^ qm) * 8)];
                    s[0][g] = __builtin_amdgcn_mfma_f32_16x16x32_bf16(qf[0][c], kf, s[0][g], 0, 0, 0);
                    s[1][g] = __builtin_amdgcn_mfma_f32_16x16x32_bf16(qf[1][c], kf, s[1][g], 0, 0, 0);
                }
            }
            if (kv0 + 63 > qa) {   // diagonal region (covers both sets; exact per-element)
#pragma unroll
                for (int s2 = 0; s2 < 2; s2++)
#pragma unroll
                    for (int g = 0; g < 4; g++)
#pragma unroll
                        for (int r = 0; r < 4; r++) {
                            int qg = qa + s2 * 16 + quad * 4 + r;
                            if (kv0 + g * 16 + qm > qg) s[s2][g][r] = -3.0e38f;
                        }
            }
#pragma unroll
            for (int s2 = 0; s2 < 2; s2++)
#pragma unroll
                for (int g = 0; g < 4; g++)
#pragma unroll
                    for (int r = 0; r < 4; r++) {
                        float p = __builtin_amdgcn_exp2f(s[s2][g][r] - M);
                        lr[s2][r] += p;
                        int rowp = s2 * 16 + quad * 4 + r;
                        P[rowp * 64 + (((g * 2 + (qm >> 3)) ^ (rowp & 7)) * 8) + (qm & 7)] = f2bf_pos(p);
                    }
            short8 pa[2][2];
#pragma unroll
            for (int s2 = 0; s2 < 2; s2++)
#pragma unroll
                for (int ka = 0; ka < 2; ka++)
                    pa[s2][ka] = *(const short8*)&P[(s2 * 16 + qm) * 64 + (((ka * 4 + quad) ^ (qm & 7)) * 8)];
#pragma unroll
            for (int t = 0; t < 8; t++) {
#pragma unroll
                for (int ka = 0; ka < 2; ka++) {
                    short8 vf = *(const short8*)&Vs[(t * 16 + qm) * 64 + (((ka * 4 + quad) ^ (qm & 7)) * 8)];
                    o[0][t] = __builtin_amdgcn_mfma_f32_16x16x32_bf16(pa[0][ka], vf, o[0][t], 0, 0, 0);
                    o[1][t] = __builtin_amdgcn_mfma_f32_16x16x32_bf16(pa[1][ka], vf, o[1][t], 0, 0, 0);
                }
            }
        }
        __syncthreads();
    }
#pragma unroll
    for (int s2 = 0; s2 < 2; s2++) {
        float rl[4];
#pragma unroll
        for (int r = 0; r < 4; r++) {
            float l = lr[s2][r];
            l += __shfl_xor(l, 1);
            l += __shfl_xor(l, 2);
            l += __shfl_xor(l, 4);
            l += __shfl_xor(l, 8);
            rl[r] = 1.0f / l;
        }
#pragma unroll
        for (int t = 0; t < 8; t++) {
#pragma unroll
            for (int r = 0; r < 4; r++) {
                size_t row = (size_t)(b * SEQ + qa + s2 * 16 + quad * 4 + r);
                y[row * D_MODEL + h * HD + t * 16 + qm] = f2bf(o[s2][t][r] * rl[r]);
            }
        }
    }
}

extern "C" void kernel_launch(void* const* d_in, const int* in_sizes, int n_in,
                              void* d_out, int out_size, void* d_ws, size_t ws_size,
                              hipStream_t stream) {
    const float* x  = (const float*)d_in[0];
    const float* Wq = (const float*)d_in[1];
    const float* Wk = (const float*)d_in[2];
    const float* Wv = (const float*)d_in[3];
    const float* Wp = (const float*)d_in[4];
    const float* qg = (const float*)d_in[5];

    char* ws = (char*)d_ws;
    unsigned short* xb   = (unsigned short*)(ws + 0);          // 16 MB (reused as y)
    unsigned short* wqkv = (unsigned short*)(ws + 16777216);   // 12 MB
    unsigned short* wp   = (unsigned short*)(ws + 29360128);   // 8 MB
    unsigned short* qbuf = (unsigned short*)(ws + 37748736);   // 16 MB
    unsigned short* kbuf = (unsigned short*)(ws + 54525952);   // 4 MB
    unsigned short* vtb  = (unsigned short*)(ws + 58720256);   // 4 MB
    float*          ropec = (float*)        (ws + 62914560);   // 512 KB
    float*          ropes = (float*)        (ws + 63438848);   // 512 KB
    unsigned short* y    = xb;                                 // alias: xb dead after GEMM1

    cast_all<<<18944, 256, 0, stream>>>(x, Wq, Wk, Wv, Wp, xb, wqkv, wp, ropec, ropes);
    gemm_qkv<<<dim3(24, 32), 256, 0, stream>>>(xb, wqkv, qg, ropec, ropes, qbuf, kbuf, vtb);
    attn<<<512, 256, 0, stream>>>(qbuf, kbuf, vtb, qg, y);
    gemm_bt<<<dim3(16, 32), 256, 0, stream>>>(y, wp, (float*)d_out, MROWS, D_MODEL, D_MODEL);
}